// Round 3
// baseline (311.960 us; speedup 1.0000x reference)
//
#include <hip/hip_runtime.h>
#include <math.h>

// Problem constants
#define N_TOK 32768
#define KCB   4096
#define SPLITS 8
#define CPS   512   // codes per split
#define TILES 32    // CPS/16

// Output layout (flat float32)
#define OFF_ZQST   0
#define OFF_ZQ     2097152
#define OFF_IDX    4194304
#define OFF_STATS  4227072
#define OFF_NEWEMB 4227074
#define OFF_NEWCS  4489218
#define OFF_NEWEMA 4493314

// Workspace layout (bytes)
#define WS_FN     0          // 8388608
#define WS_ESUM   8388608    // 1048576
#define WS_USAGE  9437184    // 16384
#define WS_CNTS   9453568    // 16 (candcnt@0, fullcnt@4)
#define WS_EHI    9453584    // 524288
#define WS_ELO    9977872    // 524288
#define WS_PK1    10502160   // 1048576
#define WS_PK2    11550736   // 1048576
#define WS_PK3    12599312   // 1048576
#define WS_IDXW   13647888   // 131072
#define WS_RIDX   13778960   // 16384
#define WS_CAND   13795344   // 524288 (int4 x 32768)
#define WS_FULL   14319632   // 131072
#define WS_NVAL   14450704   // 4

#define MARGIN 3e-4f

typedef __attribute__((ext_vector_type(8))) short short8;
typedef __attribute__((ext_vector_type(4))) float float4v;

__device__ __forceinline__ float wave_sum(float v) {
#pragma unroll
  for (int off = 32; off > 0; off >>= 1) v += __shfl_xor(v, off, 64);
  return v;
}
__device__ __forceinline__ double wave_sum_d(double v) {
#pragma unroll
  for (int off = 32; off > 0; off >>= 1) v += __shfl_xor(v, off, 64);
  return v;
}

// round-to-nearest-even f32 -> bf16 bits
__device__ __forceinline__ unsigned short f2bf(float f) {
  unsigned u = __float_as_uint(f);
  unsigned r = (u + 0x7fffu + ((u >> 16) & 1u)) >> 16;
  return (unsigned short)r;
}
__device__ __forceinline__ float bf2f(unsigned short h) {
  return __uint_as_float(((unsigned)h) << 16);
}
__device__ __forceinline__ float unkey(int k) {
  return __int_as_float(k & 0xFFFFFE00);
}

// ---------------- Threefry-2x32 (20 rounds), bit-exact vs JAX ----------------
__device__ __forceinline__ unsigned rotl32(unsigned x, int d) {
  return (x << d) | (x >> (32 - d));
}
__device__ __forceinline__ void tf2x32(unsigned k0, unsigned k1,
                                       unsigned x0, unsigned x1,
                                       unsigned& o0, unsigned& o1) {
  unsigned ks2 = k0 ^ k1 ^ 0x1BD11BDAu;
  unsigned v0 = x0 + k0, v1 = x1 + k1;
  v0 += v1; v1 = rotl32(v1, 13) ^ v0;
  v0 += v1; v1 = rotl32(v1, 15) ^ v0;
  v0 += v1; v1 = rotl32(v1, 26) ^ v0;
  v0 += v1; v1 = rotl32(v1, 6) ^ v0;
  v0 += k1; v1 += ks2 + 1u;
  v0 += v1; v1 = rotl32(v1, 17) ^ v0;
  v0 += v1; v1 = rotl32(v1, 29) ^ v0;
  v0 += v1; v1 = rotl32(v1, 16) ^ v0;
  v0 += v1; v1 = rotl32(v1, 24) ^ v0;
  v0 += ks2; v1 += k0 + 2u;
  v0 += v1; v1 = rotl32(v1, 13) ^ v0;
  v0 += v1; v1 = rotl32(v1, 15) ^ v0;
  v0 += v1; v1 = rotl32(v1, 26) ^ v0;
  v0 += v1; v1 = rotl32(v1, 6) ^ v0;
  v0 += k0; v1 += k1 + 3u;
  v0 += v1; v1 = rotl32(v1, 17) ^ v0;
  v0 += v1; v1 = rotl32(v1, 29) ^ v0;
  v0 += v1; v1 = rotl32(v1, 16) ^ v0;
  v0 += v1; v1 = rotl32(v1, 24) ^ v0;
  v0 += k1; v1 += ks2 + 4u;
  v0 += v1; v1 = rotl32(v1, 13) ^ v0;
  v0 += v1; v1 = rotl32(v1, 15) ^ v0;
  v0 += v1; v1 = rotl32(v1, 26) ^ v0;
  v0 += v1; v1 = rotl32(v1, 6) ^ v0;
  v0 += ks2; v1 += k0 + 5u;
  o0 = v0; o1 = v1;
}

__global__ void k_ridx(int* __restrict__ ridx) {
  int j = blockIdx.x * 256 + threadIdx.x;  // 0..2047
  unsigned a0, b0, a1, b1;
  tf2x32(0u, 1u, 0u, 2u, a0, b0);
  tf2x32(0u, 1u, 1u, 3u, a1, b1);
  unsigned o0, o1;
  tf2x32(b0, b1, (unsigned)j, (unsigned)(j + 2048), o0, o1);
  ridx[j] = (int)(o0 & 32767u);
  ridx[j + 2048] = (int)(o1 & 32767u);
}

// ---------------- emb -> bf16 hi/lo ----------------
__global__ __launch_bounds__(256) void k_prep_emb(const float* __restrict__ emb,
                                                  unsigned short* __restrict__ ehi,
                                                  unsigned short* __restrict__ elo) {
  int i = blockIdx.x * 256 + threadIdx.x;
  float x = emb[i];
  unsigned short h = f2bf(x);
  ehi[i] = h;
  elo[i] = f2bf(x - bf2f(h));
}

// ---------------- normalize rows of z_e -> fn ----------------
__global__ __launch_bounds__(256) void k_norm(const float* __restrict__ z_e,
                                              float* __restrict__ fn) {
  int t = threadIdx.x;
  int n = blockIdx.x * 4 + (t >> 6);
  int lane = t & 63;
  float x = z_e[n * 64 + lane];
  float ss = wave_sum(x * x);
  fn[n * 64 + lane] = x / fmaxf(sqrtf(ss), 1e-8f);
}

// ---------------- MFMA dots + per-split packed top-3 ----------------
// grid (128, 8). Wave: 64 queries (4 subtiles of 16), sweeps 512 codes (32 tiles).
// key = (bits(dot+2.0) & ~0x1FF) | (511 - idx_in_split): value-major, small-idx-major.
__global__ __launch_bounds__(256, 3) void k_dots_mfma(const float* __restrict__ fn,
                                                      const unsigned short* __restrict__ ehi,
                                                      const unsigned short* __restrict__ elo,
                                                      int* __restrict__ pk1,
                                                      int* __restrict__ pk2,
                                                      int* __restrict__ pk3) {
  __shared__ int red[4][64][16][3];  // 48 KiB
  int t = threadIdx.x;
  int wave = t >> 6, lane = t & 63;
  int qwave = blockIdx.x * 256 + wave * 64;
  int split = blockIdx.y;
  int g = lane >> 4;  // k-chunk group
  int n = lane & 15;

  // A fragments: lane -> A[m=n][k=ks*32+g*8+j]
  short8 ahi[4][2], alo[4][2];
#pragma unroll
  for (int s = 0; s < 4; s++) {
#pragma unroll
    for (int ks = 0; ks < 2; ks++) {
      const float* src = fn + (qwave + s * 16 + n) * 64 + ks * 32 + g * 8;
      short8 h, l;
#pragma unroll
      for (int j = 0; j < 8; j++) {
        float f = src[j];
        unsigned short hu = f2bf(f);
        h[j] = (short)hu;
        l[j] = (short)f2bf(f - bf2f(hu));
      }
      ahi[s][ks] = h;
      alo[s][ks] = l;
    }
  }

  int run1[4][4], run2[4][4], run3[4][4];
#pragma unroll
  for (int s = 0; s < 4; s++)
#pragma unroll
    for (int r = 0; r < 4; r++) { run1[s][r] = 0; run2[s][r] = 0; run3[s][r] = 0; }

  const unsigned short* bh = ehi + (split * CPS + n) * 64 + g * 8;
  const unsigned short* bl = elo + (split * CPS + n) * 64 + g * 8;

  short8 bh0 = *(const short8*)(bh);
  short8 bh1 = *(const short8*)(bh + 32);
  short8 bl0 = *(const short8*)(bl);
  short8 bl1 = *(const short8*)(bl + 32);

  for (int kt = 0; kt < TILES; kt++) {
    short8 nh0, nh1, nl0, nl1;
    if (kt + 1 < TILES) {  // register prefetch of next tile's B
      int off = (kt + 1) * 1024;
      nh0 = *(const short8*)(bh + off);
      nh1 = *(const short8*)(bh + off + 32);
      nl0 = *(const short8*)(bl + off);
      nl1 = *(const short8*)(bl + off + 32);
    }

    float4v acc[4];
#pragma unroll
    for (int s = 0; s < 4; s++) acc[s] = (float4v){0.f, 0.f, 0.f, 0.f};
#pragma unroll
    for (int s = 0; s < 4; s++) acc[s] = __builtin_amdgcn_mfma_f32_16x16x32_bf16(alo[s][0], bh0, acc[s], 0, 0, 0);
#pragma unroll
    for (int s = 0; s < 4; s++) acc[s] = __builtin_amdgcn_mfma_f32_16x16x32_bf16(alo[s][1], bh1, acc[s], 0, 0, 0);
#pragma unroll
    for (int s = 0; s < 4; s++) acc[s] = __builtin_amdgcn_mfma_f32_16x16x32_bf16(ahi[s][0], bl0, acc[s], 0, 0, 0);
#pragma unroll
    for (int s = 0; s < 4; s++) acc[s] = __builtin_amdgcn_mfma_f32_16x16x32_bf16(ahi[s][1], bl1, acc[s], 0, 0, 0);
#pragma unroll
    for (int s = 0; s < 4; s++) acc[s] = __builtin_amdgcn_mfma_f32_16x16x32_bf16(ahi[s][0], bh0, acc[s], 0, 0, 0);
#pragma unroll
    for (int s = 0; s < 4; s++) acc[s] = __builtin_amdgcn_mfma_f32_16x16x32_bf16(ahi[s][1], bh1, acc[s], 0, 0, 0);

    int invbase = 511 - kt * 16 - n;  // unique 9-bit inverse idx within split
#pragma unroll
    for (int s = 0; s < 4; s++)
#pragma unroll
      for (int r = 0; r < 4; r++) {
        int kb = (__float_as_int(acc[s][r] + 2.0f) & 0xFFFFFE00) | invbase;
        run3[s][r] = max(run3[s][r], min(run2[s][r], kb));
        run2[s][r] = max(run2[s][r], min(run1[s][r], kb));
        run1[s][r] = max(run1[s][r], kb);
      }

    bh0 = nh0; bh1 = nh1; bl0 = nl0; bl1 = nl1;
  }

  // per-wave LDS reduce (wave reads only what it wrote -> no barrier needed)
#pragma unroll
  for (int s = 0; s < 4; s++)
#pragma unroll
    for (int r = 0; r < 4; r++) {
      int q = s * 16 + g * 4 + r;
      red[wave][q][n][0] = run1[s][r];
      red[wave][q][n][1] = run2[s][r];
      red[wave][q][n][2] = run3[s][r];
    }
  __builtin_amdgcn_s_waitcnt(0);  // drain LDS writes (same wave)

  int b1 = 0, b2 = 0, b3 = 0;
  for (int j = 0; j < 16; j++) {
    int k1 = red[wave][lane][j][0];
    int k2 = red[wave][lane][j][1];
    int k3 = red[wave][lane][j][2];
    if (k1 > b3) {
      if (k1 > b1) { b3 = b2; b2 = b1; b1 = k1; }
      else if (k1 > b2) { b3 = b2; b2 = k1; }
      else b3 = k1;
      if (k2 > b3) {
        if (k2 > b2) { b3 = b2; b2 = k2; }
        else b3 = k2;
        if (k3 > b3) b3 = k3;
      }
    }
  }
  int qg = qwave + lane;
  pk1[split * N_TOK + qg] = b1;
  pk2[split * N_TOK + qg] = b2;
  pk3[split * N_TOK + qg] = b3;
}

// ---------------- merge splits, classify near-ties ----------------
__global__ __launch_bounds__(256) void k_merge(const int* __restrict__ pk1,
                                               const int* __restrict__ pk2,
                                               const int* __restrict__ pk3,
                                               int* __restrict__ idxw,
                                               int* __restrict__ cnts,
                                               int4* __restrict__ cand,
                                               int* __restrict__ full) {
  int q = blockIdx.x * 256 + threadIdx.x;
  int b1 = 0, b2 = 0, b3 = 0, s1 = 0, s2 = 0, s3 = 0;
  for (int s = 0; s < SPLITS; s++) {
    int k1 = pk1[s * N_TOK + q];
    int k2 = pk2[s * N_TOK + q];
    int k3 = pk3[s * N_TOK + q];
    if (k1 > b3) {
      if (k1 > b1) { b3 = b2; s3 = s2; b2 = b1; s2 = s1; b1 = k1; s1 = s; }
      else if (k1 > b2) { b3 = b2; s3 = s2; b2 = k1; s2 = s; }
      else { b3 = k1; s3 = s; }
      if (k2 > b3) {
        if (k2 > b2) { b3 = b2; s3 = s2; b2 = k2; s2 = s; }
        else { b3 = k2; s3 = s; }
        if (k3 > b3) { b3 = k3; s3 = s; }
      }
    }
  }
  int i1 = s1 * CPS + 511 - (b1 & 511);
  int i2 = s2 * CPS + 511 - (b2 & 511);
  int i3 = s3 * CPS + 511 - (b3 & 511);
  idxw[q] = i1;
  float v1 = unkey(b1), v2 = unkey(b2), v3 = unkey(b3);
  if (v1 - v2 < MARGIN) {
    if (v1 - v3 >= MARGIN) {
      int p = atomicAdd(&cnts[0], 1);
      cand[p] = make_int4(q, i1, i2, i3);
    } else {
      int p = atomicAdd(&cnts[1], 1);
      full[p] = q;
    }
  }
}

// ---------------- exact fp64 rescore of 3 candidates (1 wave / query) -------
__global__ __launch_bounds__(256) void k_fix_cand(const int* __restrict__ cnts,
                                                  const int4* __restrict__ cand,
                                                  const float* __restrict__ fn,
                                                  const float* __restrict__ emb,
                                                  int* __restrict__ idxw) {
  int wave = threadIdx.x >> 6, lane = threadIdx.x & 63;
  int cnt = cnts[0];
  for (int i = blockIdx.x * 4 + wave; i < cnt; i += gridDim.x * 4) {
    int4 e = cand[i];
    double x = (double)fn[e.x * 64 + lane];
    double d1 = wave_sum_d(x * (double)emb[e.y * 64 + lane]);
    double d2 = wave_sum_d(x * (double)emb[e.z * 64 + lane]);
    double d3 = wave_sum_d(x * (double)emb[e.w * 64 + lane]);
    int bi = e.y;
    double bd = d1;
    if (d2 > bd || (d2 == bd && e.z < bi)) { bd = d2; bi = e.z; }
    if (d3 > bd || (d3 == bd && e.w < bi)) { bd = d3; bi = e.w; }
    if (lane == 0) idxw[e.x] = bi;
  }
}

// ---------------- exact fp64 full rescan (expected ~0 queries) ----------------
__global__ __launch_bounds__(256) void k_fix_full(const int* __restrict__ cnts,
                                                  const int* __restrict__ full,
                                                  const float* __restrict__ fn,
                                                  const float* __restrict__ emb,
                                                  int* __restrict__ idxw) {
  __shared__ float sfn[64];
  __shared__ double sv[256];
  __shared__ int si[256];
  int t = threadIdx.x;
  int cnt = cnts[1];
  for (int i = blockIdx.x; i < cnt; i += gridDim.x) {
    int q = full[i];
    __syncthreads();
    if (t < 64) sfn[t] = fn[q * 64 + t];
    __syncthreads();
    double best = -1e300;
    int bi = 0;
    for (int j = 0; j < 16; j++) {
      int c = t + 256 * j;
      const float* er = emb + c * 64;
      double s0 = 0, s1 = 0, s2 = 0, s3 = 0;
      for (int k = 0; k < 16; k++) {
        s0 += (double)er[k] * (double)sfn[k];
        s1 += (double)er[k + 16] * (double)sfn[k + 16];
        s2 += (double)er[k + 32] * (double)sfn[k + 32];
        s3 += (double)er[k + 48] * (double)sfn[k + 48];
      }
      double d = (s0 + s1) + (s2 + s3);
      if (d > best || (d == best && c < bi)) { best = d; bi = c; }
    }
    sv[t] = best;
    si[t] = bi;
    __syncthreads();
    for (int s2r = 128; s2r > 0; s2r >>= 1) {
      if (t < s2r) {
        if (sv[t + s2r] > sv[t] || (sv[t + s2r] == sv[t] && si[t + s2r] < si[t])) {
          sv[t] = sv[t + s2r];
          si[t] = si[t + s2r];
        }
      }
      __syncthreads();
    }
    if (t == 0) idxw[q] = si[0];
  }
}

// ---------------- write z_q, z_q_st, indices ----------------
__global__ __launch_bounds__(256) void k_write(const int* __restrict__ idxw,
                                               const float* __restrict__ z_e,
                                               const float* __restrict__ emb,
                                               float* __restrict__ out) {
  int t = threadIdx.x;
  int nn = blockIdx.x * 4 + (t >> 6);
  int lane = t & 63;
  int bi = idxw[nn];
  float v = emb[bi * 64 + lane];
  float ze = z_e[nn * 64 + lane];
  out[OFF_ZQST + nn * 64 + lane] = ze + (v - ze);
  out[OFF_ZQ + nn * 64 + lane] = v;
  if (lane == 0) out[OFF_IDX + nn] = (float)bi;
}

// ---------------- scatter: usage bincount + embed_sum ----------------
__global__ __launch_bounds__(256) void k_scatter(const int* __restrict__ idxw,
                                                 const float* __restrict__ fn,
                                                 float* __restrict__ esum,
                                                 float* __restrict__ usage) {
  int t = threadIdx.x;
  int nn = blockIdx.x * 4 + (t >> 6);
  int lane = t & 63;
  int bi = idxw[nn];
  atomicAdd(&esum[bi * 64 + lane], fn[nn * 64 + lane]);
  if (lane == 0) atomicAdd(&usage[bi], 1.0f);
}

// ---------------- stats + n = sum(new_cs) ----------------
__device__ __forceinline__ float block_reduce1024(float v, float* r, int t) {
  r[t] = v;
  __syncthreads();
  for (int s = 512; s > 0; s >>= 1) {
    if (t < s) r[t] += r[t + s];
    __syncthreads();
  }
  float res = r[0];
  __syncthreads();
  return res;
}

__global__ __launch_bounds__(1024) void k_stats(const float* __restrict__ usage,
                                                const float* __restrict__ ema_cs,
                                                float* __restrict__ out,
                                                float* __restrict__ nval) {
  __shared__ float r[1024];
  int t = threadIdx.x;
  float su = 0.f, sd = 0.f, scs = 0.f;
  for (int i = t; i < KCB; i += 1024) {
    float u = usage[i];
    su += u;
    sd += (u == 0.f) ? 1.f : 0.f;
    scs += 0.99f * ema_cs[i] + 0.01f * u;
  }
  float tot_u = block_reduce1024(su, r, t);
  float tot_d = block_reduce1024(sd, r, t);
  float tot_cs = block_reduce1024(scs, r, t);
  float denom = fmaxf(tot_u, 1.0f);
  float ent = 0.f;
  for (int i = t; i < KCB; i += 1024) {
    float p = usage[i] / denom;
    if (p > 0.f) ent += p * logf(p);
  }
  float tot_e = block_reduce1024(ent, r, t);
  if (t == 0) {
    out[OFF_STATS + 0] = expf(-tot_e);
    out[OFF_STATS + 1] = tot_d * (1.0f / 4096.0f);
    nval[0] = tot_cs;
  }
}

// ---------------- new_cs, new_ema_emb, new_embedding ----------------
__global__ __launch_bounds__(256) void k_final(const float* __restrict__ usage,
                                               const float* __restrict__ ema_cs,
                                               const float* __restrict__ ema_emb,
                                               const float* __restrict__ esum,
                                               const float* __restrict__ fn,
                                               const int* __restrict__ ridx,
                                               const float* __restrict__ nval,
                                               float* __restrict__ out) {
  int t = threadIdx.x;
  int k = blockIdx.x * 4 + (t >> 6);
  int lane = t & 63;
  float u = usage[k];
  float ncs = 0.99f * ema_cs[k] + 0.01f * u;
  if (lane == 0) out[OFF_NEWCS + k] = ncs;
  float nee = 0.99f * ema_emb[k * 64 + lane] + 0.01f * esum[k * 64 + lane];
  out[OFF_NEWEMA + k * 64 + lane] = nee;

  float n = nval[0];
  float smoothed = (ncs + 1e-5f) / (n + 4096.0f * 1e-5f);
  float ne = nee / fmaxf(smoothed, 1e-5f);
  float ss = wave_sum(ne * ne);
  ne = ne / fmaxf(sqrtf(ss), 1e-8f);

  float res;
  if (u <= 0.f) {
    int rsrc = ridx[k];
    float v = fn[rsrc * 64 + lane];
    float s2 = wave_sum(v * v);
    res = v / fmaxf(sqrtf(s2), 1e-8f);
  } else {
    res = ne;
  }
  out[OFF_NEWEMB + k * 64 + lane] = res;
}

extern "C" void kernel_launch(void* const* d_in, const int* in_sizes, int n_in,
                              void* d_out, int out_size, void* d_ws, size_t ws_size,
                              hipStream_t stream) {
  const float* z_e = (const float*)d_in[0];
  const float* emb = (const float*)d_in[1];
  const float* ema_cs = (const float*)d_in[2];
  const float* ema_emb = (const float*)d_in[3];
  float* out = (float*)d_out;
  char* ws = (char*)d_ws;

  float* fn = (float*)(ws + WS_FN);
  float* esum = (float*)(ws + WS_ESUM);
  float* usage = (float*)(ws + WS_USAGE);
  int* cnts = (int*)(ws + WS_CNTS);
  unsigned short* ehi = (unsigned short*)(ws + WS_EHI);
  unsigned short* elo = (unsigned short*)(ws + WS_ELO);
  int* pk1 = (int*)(ws + WS_PK1);
  int* pk2 = (int*)(ws + WS_PK2);
  int* pk3 = (int*)(ws + WS_PK3);
  int* idxw = (int*)(ws + WS_IDXW);
  int* ridx = (int*)(ws + WS_RIDX);
  int4* cand = (int4*)(ws + WS_CAND);
  int* full = (int*)(ws + WS_FULL);
  float* nval = (float*)(ws + WS_NVAL);

  // zero esum + usage + counters (contiguous)
  hipMemsetAsync(ws + WS_ESUM, 0, 1048576 + 16384 + 16, stream);

  k_ridx<<<8, 256, 0, stream>>>(ridx);
  k_prep_emb<<<1024, 256, 0, stream>>>(emb, ehi, elo);
  k_norm<<<8192, 256, 0, stream>>>(z_e, fn);
  k_dots_mfma<<<dim3(128, SPLITS), 256, 0, stream>>>(fn, ehi, elo, pk1, pk2, pk3);
  k_merge<<<128, 256, 0, stream>>>(pk1, pk2, pk3, idxw, cnts, cand, full);
  k_fix_cand<<<256, 256, 0, stream>>>(cnts, cand, fn, emb, idxw);
  k_fix_full<<<128, 256, 0, stream>>>(cnts, full, fn, emb, idxw);
  k_write<<<8192, 256, 0, stream>>>(idxw, z_e, emb, out);
  k_scatter<<<8192, 256, 0, stream>>>(idxw, fn, esum, usage);
  k_stats<<<1, 1024, 0, stream>>>(usage, ema_cs, out, nval);
  k_final<<<1024, 256, 0, stream>>>(usage, ema_cs, ema_emb, esum, fn, ridx, nval, out);
}

// Round 4
// 211.178 us; speedup vs baseline: 1.4772x; 1.4772x over previous
//
#include <hip/hip_runtime.h>
#include <math.h>

// Problem constants
#define N_TOK 32768
#define KCB   4096
#define SPLITS 8
#define CPS   512   // codes per split
#define TILES 32    // CPS/16

// Output layout (flat float32)
#define OFF_ZQST   0
#define OFF_ZQ     2097152
#define OFF_IDX    4194304
#define OFF_STATS  4227072
#define OFF_NEWEMB 4227074
#define OFF_NEWCS  4489218
#define OFF_NEWEMA 4493314

// Workspace layout (bytes)
#define WS_FN       0          // 8388608
#define WS_ESUM     8388608    // 1048576  (zeroed)
#define WS_USAGE    9437184    // 16384    (zeroed)
#define WS_CNTS     9453568    // 16       (zeroed)
#define WS_FULLKEY  9453584    // 262144   (zeroed, u64 x 32768)
#define WS_EHI      9715728    // 524288
#define WS_ELO      10240016   // 524288
#define WS_PK1      10764304   // 1048576
#define WS_PK2      11812880   // 1048576
#define WS_PK3      12861456   // 1048576
#define WS_IDXW     13910032   // 131072
#define WS_RIDX     14041104   // 16384
#define WS_CAND     14057488   // 524288 (int4 x 32768)
#define WS_FULL     14581776   // 131072
#define WS_NVAL     14712848   // 4
#define ZERO_BYTES  (1048576 + 16384 + 16 + 262144)

#define MARGIN 3e-4f

typedef __attribute__((ext_vector_type(8))) short short8;
typedef __attribute__((ext_vector_type(4))) float float4v;

__device__ __forceinline__ float wave_sum(float v) {
#pragma unroll
  for (int off = 32; off > 0; off >>= 1) v += __shfl_xor(v, off, 64);
  return v;
}
__device__ __forceinline__ double wave_sum_d(double v) {
#pragma unroll
  for (int off = 32; off > 0; off >>= 1) v += __shfl_xor(v, off, 64);
  return v;
}

// round-to-nearest-even f32 -> bf16 bits
__device__ __forceinline__ unsigned short f2bf(float f) {
  unsigned u = __float_as_uint(f);
  unsigned r = (u + 0x7fffu + ((u >> 16) & 1u)) >> 16;
  return (unsigned short)r;
}
__device__ __forceinline__ float bf2f(unsigned short h) {
  return __uint_as_float(((unsigned)h) << 16);
}
__device__ __forceinline__ float unkey(int k) {
  return __int_as_float(k & 0xFFFFFE00);
}

// ---------------- Threefry-2x32 (20 rounds), bit-exact vs JAX ----------------
__device__ __forceinline__ unsigned rotl32(unsigned x, int d) {
  return (x << d) | (x >> (32 - d));
}
__device__ __forceinline__ void tf2x32(unsigned k0, unsigned k1,
                                       unsigned x0, unsigned x1,
                                       unsigned& o0, unsigned& o1) {
  unsigned ks2 = k0 ^ k1 ^ 0x1BD11BDAu;
  unsigned v0 = x0 + k0, v1 = x1 + k1;
  v0 += v1; v1 = rotl32(v1, 13) ^ v0;
  v0 += v1; v1 = rotl32(v1, 15) ^ v0;
  v0 += v1; v1 = rotl32(v1, 26) ^ v0;
  v0 += v1; v1 = rotl32(v1, 6) ^ v0;
  v0 += k1; v1 += ks2 + 1u;
  v0 += v1; v1 = rotl32(v1, 17) ^ v0;
  v0 += v1; v1 = rotl32(v1, 29) ^ v0;
  v0 += v1; v1 = rotl32(v1, 16) ^ v0;
  v0 += v1; v1 = rotl32(v1, 24) ^ v0;
  v0 += ks2; v1 += k0 + 2u;
  v0 += v1; v1 = rotl32(v1, 13) ^ v0;
  v0 += v1; v1 = rotl32(v1, 15) ^ v0;
  v0 += v1; v1 = rotl32(v1, 26) ^ v0;
  v0 += v1; v1 = rotl32(v1, 6) ^ v0;
  v0 += k0; v1 += k1 + 3u;
  v0 += v1; v1 = rotl32(v1, 17) ^ v0;
  v0 += v1; v1 = rotl32(v1, 29) ^ v0;
  v0 += v1; v1 = rotl32(v1, 16) ^ v0;
  v0 += v1; v1 = rotl32(v1, 24) ^ v0;
  v0 += k1; v1 += ks2 + 4u;
  v0 += v1; v1 = rotl32(v1, 13) ^ v0;
  v0 += v1; v1 = rotl32(v1, 15) ^ v0;
  v0 += v1; v1 = rotl32(v1, 26) ^ v0;
  v0 += v1; v1 = rotl32(v1, 6) ^ v0;
  v0 += ks2; v1 += k0 + 5u;
  o0 = v0; o1 = v1;
}

__global__ void k_ridx(int* __restrict__ ridx) {
  int j = blockIdx.x * 256 + threadIdx.x;  // 0..2047
  unsigned a0, b0, a1, b1;
  tf2x32(0u, 1u, 0u, 2u, a0, b0);
  tf2x32(0u, 1u, 1u, 3u, a1, b1);
  unsigned o0, o1;
  tf2x32(b0, b1, (unsigned)j, (unsigned)(j + 2048), o0, o1);
  ridx[j] = (int)(o0 & 32767u);
  ridx[j + 2048] = (int)(o1 & 32767u);
}

// ---------------- emb -> bf16 hi/lo ----------------
__global__ __launch_bounds__(256) void k_prep_emb(const float* __restrict__ emb,
                                                  unsigned short* __restrict__ ehi,
                                                  unsigned short* __restrict__ elo) {
  int i = blockIdx.x * 256 + threadIdx.x;
  float x = emb[i];
  unsigned short h = f2bf(x);
  ehi[i] = h;
  elo[i] = f2bf(x - bf2f(h));
}

// ---------------- normalize rows of z_e -> fn ----------------
__global__ __launch_bounds__(256) void k_norm(const float* __restrict__ z_e,
                                              float* __restrict__ fn) {
  int t = threadIdx.x;
  int n = blockIdx.x * 4 + (t >> 6);
  int lane = t & 63;
  float x = z_e[n * 64 + lane];
  float ss = wave_sum(x * x);
  fn[n * 64 + lane] = x / fmaxf(sqrtf(ss), 1e-8f);
}

// ---------------- MFMA dots + per-split packed top-3 ----------------
// grid (128, 8). Wave: 64 queries (4 subtiles of 16), sweeps 512 codes (32 tiles).
// key = (bits(dot+2.0) & ~0x1FF) | (511 - idx_in_split): value-major, small-idx-major.
__global__ __launch_bounds__(256, 3) void k_dots_mfma(const float* __restrict__ fn,
                                                      const unsigned short* __restrict__ ehi,
                                                      const unsigned short* __restrict__ elo,
                                                      int* __restrict__ pk1,
                                                      int* __restrict__ pk2,
                                                      int* __restrict__ pk3) {
  __shared__ int red[4][64][16][3];  // 48 KiB
  int t = threadIdx.x;
  int wave = t >> 6, lane = t & 63;
  int qwave = blockIdx.x * 256 + wave * 64;
  int split = blockIdx.y;
  int g = lane >> 4;  // k-chunk group
  int n = lane & 15;

  // A fragments: lane -> A[m=n][k=ks*32+g*8+j]
  short8 ahi[4][2], alo[4][2];
#pragma unroll
  for (int s = 0; s < 4; s++) {
#pragma unroll
    for (int ks = 0; ks < 2; ks++) {
      const float* src = fn + (qwave + s * 16 + n) * 64 + ks * 32 + g * 8;
      short8 h, l;
#pragma unroll
      for (int j = 0; j < 8; j++) {
        float f = src[j];
        unsigned short hu = f2bf(f);
        h[j] = (short)hu;
        l[j] = (short)f2bf(f - bf2f(hu));
      }
      ahi[s][ks] = h;
      alo[s][ks] = l;
    }
  }

  int run1[4][4], run2[4][4], run3[4][4];
#pragma unroll
  for (int s = 0; s < 4; s++)
#pragma unroll
    for (int r = 0; r < 4; r++) { run1[s][r] = 0; run2[s][r] = 0; run3[s][r] = 0; }

  const unsigned short* bh = ehi + (split * CPS + n) * 64 + g * 8;
  const unsigned short* bl = elo + (split * CPS + n) * 64 + g * 8;

  short8 bh0 = *(const short8*)(bh);
  short8 bh1 = *(const short8*)(bh + 32);
  short8 bl0 = *(const short8*)(bl);
  short8 bl1 = *(const short8*)(bl + 32);

  for (int kt = 0; kt < TILES; kt++) {
    short8 nh0, nh1, nl0, nl1;
    if (kt + 1 < TILES) {  // register prefetch of next tile's B
      int off = (kt + 1) * 1024;
      nh0 = *(const short8*)(bh + off);
      nh1 = *(const short8*)(bh + off + 32);
      nl0 = *(const short8*)(bl + off);
      nl1 = *(const short8*)(bl + off + 32);
    }

    float4v acc[4];
#pragma unroll
    for (int s = 0; s < 4; s++) acc[s] = (float4v){0.f, 0.f, 0.f, 0.f};
#pragma unroll
    for (int s = 0; s < 4; s++) acc[s] = __builtin_amdgcn_mfma_f32_16x16x32_bf16(alo[s][0], bh0, acc[s], 0, 0, 0);
#pragma unroll
    for (int s = 0; s < 4; s++) acc[s] = __builtin_amdgcn_mfma_f32_16x16x32_bf16(alo[s][1], bh1, acc[s], 0, 0, 0);
#pragma unroll
    for (int s = 0; s < 4; s++) acc[s] = __builtin_amdgcn_mfma_f32_16x16x32_bf16(ahi[s][0], bl0, acc[s], 0, 0, 0);
#pragma unroll
    for (int s = 0; s < 4; s++) acc[s] = __builtin_amdgcn_mfma_f32_16x16x32_bf16(ahi[s][1], bl1, acc[s], 0, 0, 0);
#pragma unroll
    for (int s = 0; s < 4; s++) acc[s] = __builtin_amdgcn_mfma_f32_16x16x32_bf16(ahi[s][0], bh0, acc[s], 0, 0, 0);
#pragma unroll
    for (int s = 0; s < 4; s++) acc[s] = __builtin_amdgcn_mfma_f32_16x16x32_bf16(ahi[s][1], bh1, acc[s], 0, 0, 0);

    int invbase = 511 - kt * 16 - n;  // unique 9-bit inverse idx within split
#pragma unroll
    for (int s = 0; s < 4; s++)
#pragma unroll
      for (int r = 0; r < 4; r++) {
        int kb = (__float_as_int(acc[s][r] + 2.0f) & 0xFFFFFE00) | invbase;
        run3[s][r] = max(run3[s][r], min(run2[s][r], kb));
        run2[s][r] = max(run2[s][r], min(run1[s][r], kb));
        run1[s][r] = max(run1[s][r], kb);
      }

    bh0 = nh0; bh1 = nh1; bl0 = nl0; bl1 = nl1;
  }

  // per-wave LDS reduce (wave reads only what it wrote -> no barrier needed)
#pragma unroll
  for (int s = 0; s < 4; s++)
#pragma unroll
    for (int r = 0; r < 4; r++) {
      int q = s * 16 + g * 4 + r;
      red[wave][q][n][0] = run1[s][r];
      red[wave][q][n][1] = run2[s][r];
      red[wave][q][n][2] = run3[s][r];
    }
  __builtin_amdgcn_s_waitcnt(0);  // drain LDS writes (same wave)

  int b1 = 0, b2 = 0, b3 = 0;
  for (int j = 0; j < 16; j++) {
    int k1 = red[wave][lane][j][0];
    int k2 = red[wave][lane][j][1];
    int k3 = red[wave][lane][j][2];
    if (k1 > b3) {
      if (k1 > b1) { b3 = b2; b2 = b1; b1 = k1; }
      else if (k1 > b2) { b3 = b2; b2 = k1; }
      else b3 = k1;
      if (k2 > b3) {
        if (k2 > b2) { b3 = b2; b2 = k2; }
        else b3 = k2;
        if (k3 > b3) b3 = k3;
      }
    }
  }
  int qg = qwave + lane;
  pk1[split * N_TOK + qg] = b1;
  pk2[split * N_TOK + qg] = b2;
  pk3[split * N_TOK + qg] = b3;
}

// ---------------- merge splits, classify near-ties ----------------
__global__ __launch_bounds__(256) void k_merge(const int* __restrict__ pk1,
                                               const int* __restrict__ pk2,
                                               const int* __restrict__ pk3,
                                               int* __restrict__ idxw,
                                               int* __restrict__ cnts,
                                               int4* __restrict__ cand,
                                               int* __restrict__ full) {
  int q = blockIdx.x * 256 + threadIdx.x;
  int b1 = 0, b2 = 0, b3 = 0, s1 = 0, s2 = 0, s3 = 0;
  for (int s = 0; s < SPLITS; s++) {
    int k1 = pk1[s * N_TOK + q];
    int k2 = pk2[s * N_TOK + q];
    int k3 = pk3[s * N_TOK + q];
    if (k1 > b3) {
      if (k1 > b1) { b3 = b2; s3 = s2; b2 = b1; s2 = s1; b1 = k1; s1 = s; }
      else if (k1 > b2) { b3 = b2; s3 = s2; b2 = k1; s2 = s; }
      else { b3 = k1; s3 = s; }
      if (k2 > b3) {
        if (k2 > b2) { b3 = b2; s3 = s2; b2 = k2; s2 = s; }
        else { b3 = k2; s3 = s; }
        if (k3 > b3) { b3 = k3; s3 = s; }
      }
    }
  }
  int i1 = s1 * CPS + 511 - (b1 & 511);
  int i2 = s2 * CPS + 511 - (b2 & 511);
  int i3 = s3 * CPS + 511 - (b3 & 511);
  idxw[q] = i1;
  float v1 = unkey(b1), v2 = unkey(b2), v3 = unkey(b3);
  if (v1 - v2 < MARGIN) {
    if (v1 - v3 >= MARGIN) {
      int p = atomicAdd(&cnts[0], 1);
      cand[p] = make_int4(q, i1, i2, i3);
    } else {
      int p = atomicAdd(&cnts[1], 1);
      full[p] = q;
    }
  }
}

// ---------------- exact fp64 rescore of 3 candidates (1 wave / query) -------
__global__ __launch_bounds__(256) void k_fix_cand(const int* __restrict__ cnts,
                                                  const int4* __restrict__ cand,
                                                  const float* __restrict__ fn,
                                                  const float* __restrict__ emb,
                                                  int* __restrict__ idxw) {
  int wave = threadIdx.x >> 6, lane = threadIdx.x & 63;
  int cnt = cnts[0];
  for (int i = blockIdx.x * 4 + wave; i < cnt; i += gridDim.x * 4) {
    int4 e = cand[i];
    double x = (double)fn[e.x * 64 + lane];
    double d1 = wave_sum_d(x * (double)emb[e.y * 64 + lane]);
    double d2 = wave_sum_d(x * (double)emb[e.z * 64 + lane]);
    double d3 = wave_sum_d(x * (double)emb[e.w * 64 + lane]);
    int bi = e.y;
    double bd = d1;
    if (d2 > bd || (d2 == bd && e.z < bi)) { bd = d2; bi = e.z; }
    if (d3 > bd || (d3 == bd && e.w < bi)) { bd = d3; bi = e.w; }
    if (lane == 0) idxw[e.x] = bi;
  }
}

// ---------------- exact fp64 full rescan, parallel over (query, chunk) ------
// work item w = (query_i * 16 + chunk); chunk = 256 codes, one per thread.
// result via atomicMax on packed u64 key: (bits(d+2.0) & ~0xFFF) | (4095-c).
__global__ __launch_bounds__(256) void k_fix_full(const int* __restrict__ cnts,
                                                  const int* __restrict__ full,
                                                  const float* __restrict__ fn,
                                                  const float* __restrict__ emb,
                                                  unsigned long long* __restrict__ fullkey) {
  __shared__ float sfn[64];
  __shared__ unsigned long long red[256];
  int t = threadIdx.x;
  int total = cnts[1] * 16;
  for (int w = blockIdx.x; w < total; w += gridDim.x) {
    int q = full[w >> 4];
    int c = (w & 15) * 256 + t;
    __syncthreads();  // protect sfn/red reuse across iterations
    if (t < 64) sfn[t] = fn[q * 64 + t];
    __syncthreads();
    const float* er = emb + c * 64;
    double s0 = 0, s1 = 0, s2 = 0, s3 = 0;
    for (int k = 0; k < 16; k++) {
      s0 += (double)er[k] * (double)sfn[k];
      s1 += (double)er[k + 16] * (double)sfn[k + 16];
      s2 += (double)er[k + 32] * (double)sfn[k + 32];
      s3 += (double)er[k + 48] * (double)sfn[k + 48];
    }
    double d = (s0 + s1) + (s2 + s3);
    unsigned long long key =
        ((unsigned long long)__double_as_longlong(d + 2.0) & ~0xFFFULL) |
        (unsigned long long)(4095 - c);
    red[t] = key;
    __syncthreads();
    for (int s = 128; s > 0; s >>= 1) {
      if (t < s) red[t] = red[t] > red[t + s] ? red[t] : red[t + s];
      __syncthreads();
    }
    if (t == 0) atomicMax(&fullkey[q], red[0]);
  }
}

// ---------------- write z_q, z_q_st, indices + scatter stats ----------------
__global__ __launch_bounds__(256) void k_write_scatter(const int* __restrict__ idxw,
                                                       const unsigned long long* __restrict__ fullkey,
                                                       const float* __restrict__ z_e,
                                                       const float* __restrict__ emb,
                                                       const float* __restrict__ fn,
                                                       float* __restrict__ out,
                                                       float* __restrict__ esum,
                                                       float* __restrict__ usage) {
  int t = threadIdx.x;
  int nn = blockIdx.x * 4 + (t >> 6);
  int lane = t & 63;
  unsigned long long fk = fullkey[nn];
  int bi = fk ? (4095 - (int)(fk & 0xFFFULL)) : idxw[nn];
  float v = emb[bi * 64 + lane];
  float ze = z_e[nn * 64 + lane];
  out[OFF_ZQST + nn * 64 + lane] = ze + (v - ze);
  out[OFF_ZQ + nn * 64 + lane] = v;
  atomicAdd(&esum[bi * 64 + lane], fn[nn * 64 + lane]);
  if (lane == 0) {
    out[OFF_IDX + nn] = (float)bi;
    atomicAdd(&usage[bi], 1.0f);
  }
}

// ---------------- stats + n = sum(new_cs); 1024 thr, wave-level reduces ----
__global__ __launch_bounds__(1024) void k_stats(const float* __restrict__ usage,
                                                const float* __restrict__ ema_cs,
                                                float* __restrict__ out,
                                                float* __restrict__ nval) {
  __shared__ float rA[16], rB[16], rC[16], bc[4];
  int t = threadIdx.x;
  int w = t >> 6, lane = t & 63;
  float su = 0.f, sd = 0.f, scs = 0.f;
  for (int i = t; i < KCB; i += 1024) {
    float u = usage[i];
    su += u;
    sd += (u == 0.f) ? 1.f : 0.f;
    scs += 0.99f * ema_cs[i] + 0.01f * u;
  }
  su = wave_sum(su); sd = wave_sum(sd); scs = wave_sum(scs);
  if (lane == 0) { rA[w] = su; rB[w] = sd; rC[w] = scs; }
  __syncthreads();
  if (t == 0) {
    float a = 0, b = 0, c = 0;
    for (int i = 0; i < 16; i++) { a += rA[i]; b += rB[i]; c += rC[i]; }
    bc[0] = fmaxf(a, 1.0f);  // denom
    bc[1] = b;               // dead count
    bc[2] = c;               // n
  }
  __syncthreads();
  float denom = bc[0];
  float ent = 0.f;
  for (int i = t; i < KCB; i += 1024) {
    float p = usage[i] / denom;
    if (p > 0.f) ent += p * logf(p);
  }
  ent = wave_sum(ent);
  if (lane == 0) rA[w] = ent;
  __syncthreads();
  if (t == 0) {
    float e = 0;
    for (int i = 0; i < 16; i++) e += rA[i];
    out[OFF_STATS + 0] = expf(-e);
    out[OFF_STATS + 1] = bc[1] * (1.0f / 4096.0f);
    nval[0] = bc[2];
  }
}

// ---------------- new_cs, new_ema_emb, new_embedding ----------------
__global__ __launch_bounds__(256) void k_final(const float* __restrict__ usage,
                                               const float* __restrict__ ema_cs,
                                               const float* __restrict__ ema_emb,
                                               const float* __restrict__ esum,
                                               const float* __restrict__ fn,
                                               const int* __restrict__ ridx,
                                               const float* __restrict__ nval,
                                               float* __restrict__ out) {
  int t = threadIdx.x;
  int k = blockIdx.x * 4 + (t >> 6);
  int lane = t & 63;
  float u = usage[k];
  float ncs = 0.99f * ema_cs[k] + 0.01f * u;
  if (lane == 0) out[OFF_NEWCS + k] = ncs;
  float nee = 0.99f * ema_emb[k * 64 + lane] + 0.01f * esum[k * 64 + lane];
  out[OFF_NEWEMA + k * 64 + lane] = nee;

  float n = nval[0];
  float smoothed = (ncs + 1e-5f) / (n + 4096.0f * 1e-5f);
  float ne = nee / fmaxf(smoothed, 1e-5f);
  float ss = wave_sum(ne * ne);
  ne = ne / fmaxf(sqrtf(ss), 1e-8f);

  float res;
  if (u <= 0.f) {
    int rsrc = ridx[k];
    float v = fn[rsrc * 64 + lane];
    float s2 = wave_sum(v * v);
    res = v / fmaxf(sqrtf(s2), 1e-8f);
  } else {
    res = ne;
  }
  out[OFF_NEWEMB + k * 64 + lane] = res;
}

extern "C" void kernel_launch(void* const* d_in, const int* in_sizes, int n_in,
                              void* d_out, int out_size, void* d_ws, size_t ws_size,
                              hipStream_t stream) {
  const float* z_e = (const float*)d_in[0];
  const float* emb = (const float*)d_in[1];
  const float* ema_cs = (const float*)d_in[2];
  const float* ema_emb = (const float*)d_in[3];
  float* out = (float*)d_out;
  char* ws = (char*)d_ws;

  float* fn = (float*)(ws + WS_FN);
  float* esum = (float*)(ws + WS_ESUM);
  float* usage = (float*)(ws + WS_USAGE);
  int* cnts = (int*)(ws + WS_CNTS);
  unsigned long long* fullkey = (unsigned long long*)(ws + WS_FULLKEY);
  unsigned short* ehi = (unsigned short*)(ws + WS_EHI);
  unsigned short* elo = (unsigned short*)(ws + WS_ELO);
  int* pk1 = (int*)(ws + WS_PK1);
  int* pk2 = (int*)(ws + WS_PK2);
  int* pk3 = (int*)(ws + WS_PK3);
  int* idxw = (int*)(ws + WS_IDXW);
  int* ridx = (int*)(ws + WS_RIDX);
  int4* cand = (int4*)(ws + WS_CAND);
  int* full = (int*)(ws + WS_FULL);
  float* nval = (float*)(ws + WS_NVAL);

  // zero esum + usage + counters + fullkey (contiguous)
  hipMemsetAsync(ws + WS_ESUM, 0, ZERO_BYTES, stream);

  k_ridx<<<8, 256, 0, stream>>>(ridx);
  k_prep_emb<<<1024, 256, 0, stream>>>(emb, ehi, elo);
  k_norm<<<8192, 256, 0, stream>>>(z_e, fn);
  k_dots_mfma<<<dim3(128, SPLITS), 256, 0, stream>>>(fn, ehi, elo, pk1, pk2, pk3);
  k_merge<<<128, 256, 0, stream>>>(pk1, pk2, pk3, idxw, cnts, cand, full);
  k_fix_cand<<<256, 256, 0, stream>>>(cnts, cand, fn, emb, idxw);
  k_fix_full<<<512, 256, 0, stream>>>(cnts, full, fn, emb, fullkey);
  k_write_scatter<<<8192, 256, 0, stream>>>(idxw, fullkey, z_e, emb, fn, out, esum, usage);
  k_stats<<<1, 1024, 0, stream>>>(usage, ema_cs, out, nval);
  k_final<<<1024, 256, 0, stream>>>(usage, ema_cs, ema_emb, esum, fn, ridx, nval, out);
}